// Round 1
// baseline (355.296 us; speedup 1.0000x reference)
//
#include <hip/hip_runtime.h>
#include <math.h>

// Capsule routing, B=2048, R=64, H=512, 3 iterations.
// One block per batch b (512 threads = one per h). Each thread holds its
// 64-element r-column in registers; only the squash norm needs a block
// reduction (over h) per iteration.

#define BB 2048
#define RR 64
#define HH 512

__global__ __launch_bounds__(512) void capsule_kernel(
    const float* __restrict__ in, float* __restrict__ out) {
    const int b = blockIdx.x;
    const int h = threadIdx.x;
    const float* col = in + (size_t)b * (RR * HH) + h;

    // Load column into registers: 64 independent coalesced dword loads.
    float x[RR];
#pragma unroll
    for (int r = 0; r < RR; ++r) {
        x[r] = col[(size_t)r * HH];
    }

    __shared__ float red[8];
    __shared__ float bc;

    const int wave = threadIdx.x >> 6;
    const int lane = threadIdx.x & 63;

    // Block-wide sum over all 512 threads; result broadcast to all.
    auto block_sum = [&](float v) -> float {
#pragma unroll
        for (int off = 32; off > 0; off >>= 1) {
            v += __shfl_down(v, off, 64);
        }
        if (lane == 0) red[wave] = v;
        __syncthreads();
        if (threadIdx.x == 0) {
            float t = 0.f;
#pragma unroll
            for (int w = 0; w < 8; ++w) t += red[w];
            bc = t;
        }
        __syncthreads();
        return bc;
        // (ordering of red/bc reuse across calls is protected by the two
        // barriers above: any later write happens after every earlier read)
    };

    // ---- iteration 0: uniform softmax (1/64) ----
    float m = 0.f;
#pragma unroll
    for (int r = 0; r < RR; ++r) m += x[r];
    m *= (1.0f / 64.0f);

    float norm = block_sum(m * m);
    float s = sqrtf(norm);
    float v0 = m * norm / ((1.0f + s) * s);

    float vacc = v0;   // accumulated b_ij coefficient: v0, then v0+v1
    float vout = v0;   // last squashed vec (answer after 2 more iters)

    // ---- iterations 1 and 2 ----
#pragma unroll
    for (int it = 0; it < 2; ++it) {
        // logits l_r = x_r * vacc ; stable softmax over r (thread-local)
        float mx = -INFINITY;
#pragma unroll
        for (int r = 0; r < RR; ++r) mx = fmaxf(mx, x[r] * vacc);

        float se = 0.f, sex = 0.f;
#pragma unroll
        for (int r = 0; r < RR; ++r) {
            float e = __expf(x[r] * vacc - mx);
            se += e;
            sex += e * x[r];
        }
        float sval = sex / se;  // Σ_r softmax_r * x_r

        float nrm = block_sum(sval * sval);
        float ss = sqrtf(nrm);
        float vv = sval * nrm / ((1.0f + ss) * ss);

        vacc += vv;
        vout = vv;
    }

    out[(size_t)b * HH + h] = vout;
}

extern "C" void kernel_launch(void* const* d_in, const int* in_sizes, int n_in,
                              void* d_out, int out_size, void* d_ws, size_t ws_size,
                              hipStream_t stream) {
    const float* in = (const float*)d_in[0];
    float* out = (float*)d_out;
    capsule_kernel<<<dim3(BB), dim3(HH), 0, stream>>>(in, out);
}

// Round 2
// 352.761 us; speedup vs baseline: 1.0072x; 1.0072x over previous
//
#include <hip/hip_runtime.h>
#include <math.h>

// Capsule routing, B=2048, R=64, H=512, 3 iterations.
// One block per batch b; 256 threads, each owning TWO h-columns (float2
// loads, 512 B per wave-instruction). Columns live in registers across all
// 3 iterations; only the squash norm needs a block reduction (over h).
//
// Softmax over r is computed WITHOUT max-subtraction: logits x*vacc are
// bounded (|x| <~ 6 over 64M N(0,1) samples, |vacc_h| <~ 2), far from fp32
// exp overflow (88). Saves 2*64 fmax + 2*64 mul per thread vs stable form.

#define BB 2048
#define RR 64
#define HH 512

__global__ __launch_bounds__(256) void capsule_kernel(
    const float* __restrict__ in, float* __restrict__ out) {
    const int b = blockIdx.x;
    const int t = threadIdx.x;
    const float2* col = (const float2*)(in + (size_t)b * (RR * HH)) + t;

    // 64 independent coalesced dwordx2 loads (each 512 B per wave).
    float2 x[RR];
#pragma unroll
    for (int r = 0; r < RR; ++r) {
        x[r] = col[(size_t)r * (HH / 2)];
    }

    __shared__ float red[4];
    __shared__ float bc;

    const int wave = t >> 6;
    const int lane = t & 63;

    // Block-wide sum over 256 threads (4 waves); result broadcast to all.
    auto block_sum = [&](float v) -> float {
#pragma unroll
        for (int off = 32; off > 0; off >>= 1) {
            v += __shfl_down(v, off, 64);
        }
        if (lane == 0) red[wave] = v;
        __syncthreads();
        if (t == 0) {
            bc = red[0] + red[1] + red[2] + red[3];
        }
        __syncthreads();
        return bc;
    };

    // ---- iteration 0: uniform softmax (1/64) ----
    float2 m = {0.f, 0.f};
#pragma unroll
    for (int r = 0; r < RR; ++r) {
        m.x += x[r].x;
        m.y += x[r].y;
    }
    m.x *= (1.0f / 64.0f);
    m.y *= (1.0f / 64.0f);

    float norm = block_sum(m.x * m.x + m.y * m.y);
    float s = sqrtf(norm);
    float coef = norm / ((1.0f + s) * s);
    float2 vacc = {m.x * coef, m.y * coef};  // accumulated b_ij coefficient
    float2 vout = vacc;                      // last squashed vec

    // ---- iterations 1 and 2 ----
#pragma unroll
    for (int it = 0; it < 2; ++it) {
        float se0 = 0.f, sex0 = 0.f, se1 = 0.f, sex1 = 0.f;
#pragma unroll
        for (int r = 0; r < RR; ++r) {
            float e0 = __expf(x[r].x * vacc.x);
            float e1 = __expf(x[r].y * vacc.y);
            se0 += e0;
            sex0 = fmaf(e0, x[r].x, sex0);
            se1 += e1;
            sex1 = fmaf(e1, x[r].y, sex1);
        }
        float2 sval = {sex0 / se0, sex1 / se1};  // sum_r softmax_r * x_r

        float nrm = block_sum(sval.x * sval.x + sval.y * sval.y);
        float ss = sqrtf(nrm);
        float cc = nrm / ((1.0f + ss) * ss);
        float2 vv = {sval.x * cc, sval.y * cc};

        vacc.x += vv.x;
        vacc.y += vv.y;
        vout = vv;
    }

    ((float2*)(out + (size_t)b * HH))[t] = vout;
}

extern "C" void kernel_launch(void* const* d_in, const int* in_sizes, int n_in,
                              void* d_out, int out_size, void* d_ws, size_t ws_size,
                              hipStream_t stream) {
    const float* in = (const float*)d_in[0];
    float* out = (float*)d_out;
    capsule_kernel<<<dim3(BB), dim3(256), 0, stream>>>(in, out);
}

// Round 3
// 352.052 us; speedup vs baseline: 1.0092x; 1.0020x over previous
//
#include <hip/hip_runtime.h>
#include <math.h>

// Capsule routing, B=2048, R=64, H=512, 3 iterations.
// One block per batch b; 1024 threads (16 waves). The r-dimension is split
// 4-ways across lane groups of each wave: thread (wave w, lane l) owns
// h-columns {2*(w*16 + (l&15)), +1} (float2) and rows r in [ (l>>4)*16, +16 ).
// x-state = 16 float2 = 32 VGPRs -> ~60 total -> 8 waves/SIMD (100% occ,
// 2 blocks/CU), 2.7x the outstanding-load depth of the previous version.
//
// Softmax partial sums (se, sex) merge across the 4 r-groups with shfl_xor
// 16/32 butterflies (fp-add commutative -> all 4 copies bitwise identical,
// so every thread deterministically carries the same vacc).
//
// Softmax over r is computed WITHOUT max-subtraction: logits x*vacc are
// bounded (|x| <~ 6, |vacc_h| <~ 11 worst case) -> far from fp32 exp
// overflow (88).

#define BB 2048
#define RR 64
#define HH 512

__global__ __launch_bounds__(1024, 8) void capsule_kernel(
    const float* __restrict__ in, float* __restrict__ out) {
    const int b = blockIdx.x;
    const int t = threadIdx.x;
    const int wave = t >> 6;
    const int lane = t & 63;
    const int rq = lane >> 4;        // r-quarter: 0..3
    const int l16 = lane & 15;
    const int h2 = wave * 16 + l16;  // float2 column index, 0..255

    const float2* in2 = (const float2*)(in + (size_t)b * (RR * HH));

    // 16 independent loads; per wave-instr: 4 dense 128 B segments.
    float2 x[16];
#pragma unroll
    for (int i = 0; i < 16; ++i) {
        x[i] = in2[(size_t)(rq * 16 + i) * (HH / 2) + h2];
    }

    __shared__ float red[16];
    __shared__ float bc;

    // Block sum over 1024 threads, scaled by 0.25 (each h held by 4 threads).
    auto block_sum_q = [&](float v) -> float {
#pragma unroll
        for (int off = 32; off > 0; off >>= 1) {
            v += __shfl_down(v, off, 64);
        }
        if (lane == 0) red[wave] = v;
        __syncthreads();
        if (t == 0) {
            float s = 0.f;
#pragma unroll
            for (int w = 0; w < 16; ++w) s += red[w];
            bc = 0.25f * s;
        }
        __syncthreads();
        return bc;
    };

    // ---- iteration 0: uniform softmax (1/64) ----
    float2 m = {0.f, 0.f};
#pragma unroll
    for (int i = 0; i < 16; ++i) {
        m.x += x[i].x;
        m.y += x[i].y;
    }
    // merge the 4 r-group partials (butterfly -> identical in all copies)
    m.x += __shfl_xor(m.x, 16, 64);
    m.x += __shfl_xor(m.x, 32, 64);
    m.y += __shfl_xor(m.y, 16, 64);
    m.y += __shfl_xor(m.y, 32, 64);
    m.x *= (1.0f / 64.0f);
    m.y *= (1.0f / 64.0f);

    float norm = block_sum_q(m.x * m.x + m.y * m.y);
    float s = sqrtf(norm);
    float coef = norm / ((1.0f + s) * s);
    float2 vacc = {m.x * coef, m.y * coef};  // accumulated b_ij coefficient
    float2 vout = vacc;                      // last squashed vec

    // ---- iterations 1 and 2 ----
#pragma unroll
    for (int it = 0; it < 2; ++it) {
        float se0 = 0.f, sex0 = 0.f, se1 = 0.f, sex1 = 0.f;
#pragma unroll
        for (int i = 0; i < 16; ++i) {
            float e0 = __expf(x[i].x * vacc.x);
            float e1 = __expf(x[i].y * vacc.y);
            se0 += e0;
            sex0 = fmaf(e0, x[i].x, sex0);
            se1 += e1;
            sex1 = fmaf(e1, x[i].y, sex1);
        }
        // merge partials across the 4 r-groups
        se0 += __shfl_xor(se0, 16, 64);
        se0 += __shfl_xor(se0, 32, 64);
        sex0 += __shfl_xor(sex0, 16, 64);
        sex0 += __shfl_xor(sex0, 32, 64);
        se1 += __shfl_xor(se1, 16, 64);
        se1 += __shfl_xor(se1, 32, 64);
        sex1 += __shfl_xor(sex1, 16, 64);
        sex1 += __shfl_xor(sex1, 32, 64);

        float2 sval = {sex0 / se0, sex1 / se1};  // sum_r softmax_r * x_r

        float nrm = block_sum_q(sval.x * sval.x + sval.y * sval.y);
        float ss = sqrtf(nrm);
        float cc = nrm / ((1.0f + ss) * ss);
        float2 vv = {sval.x * cc, sval.y * cc};

        vacc.x += vv.x;
        vacc.y += vv.y;
        vout = vv;
    }

    if (rq == 0) {
        ((float2*)(out + (size_t)b * HH))[h2] = vout;
    }
}

extern "C" void kernel_launch(void* const* d_in, const int* in_sizes, int n_in,
                              void* d_out, int out_size, void* d_ws, size_t ws_size,
                              hipStream_t stream) {
    const float* in = (const float*)d_in[0];
    float* out = (float*)d_out;
    capsule_kernel<<<dim3(BB), dim3(1024), 0, stream>>>(in, out);
}